// Round 3
// baseline (1538.216 us; speedup 1.0000x reference)
//
#include <hip/hip_runtime.h>
#include <math.h>

typedef unsigned short u16;
typedef unsigned int   u32;
typedef __attribute__((ext_vector_type(8))) short short8;
typedef __attribute__((ext_vector_type(4))) float f32x4;

#define DEV static __device__ __forceinline__

DEV float b2f(u16 u) { union { u32 i; float f; } c; c.i = ((u32)u) << 16; return c.f; }
DEV u16 f2b(float f) {
    union { float f; u32 i; } c; c.f = f;
    return (u16)((c.i + 0x7fffu + ((c.i >> 16) & 1u)) >> 16);
}
DEV f32x4 fzero() { f32x4 z = {0.f, 0.f, 0.f, 0.f}; return z; }
DEV f32x4 mfma16(short8 a, short8 b, f32x4 c) {
    return __builtin_amdgcn_mfma_f32_16x16x32_bf16(a, b, c, 0, 0, 0);
}
DEV short8 ld8(const u16* p) { return *reinterpret_cast<const short8*>(p); }

// Runtime dtype probe: if `t` really holds f32, the even u16s are low-mantissa
// bits -> random bf16 exponents -> ~50% have |v|>=64 (or NaN). True bf16 data
// (x ~ N(0,1), |x|<~6) gives 0 hits. Deterministic & identical in every block.
DEV bool detect_f32(const u16* t) {
    int g = 0;
    #pragma unroll
    for (int i = 0; i < 64; ++i) {
        float v = b2f(t[2 * i]);
        if (!(fabsf(v) < 64.0f)) ++g;   // NaN fails the compare -> counted
    }
    return g >= 8;
}

// mode-aware scalar element load (f32m: buffer is float32)
DEV float ldx(const u16* p, int i, bool f32m) {
    return f32m ? reinterpret_cast<const float*>(p)[i] : b2f(p[i]);
}

// ---------------------------------------------------------------------------
// Weight pre-transpose -> bf16 wT[n][k] so MFMA B-frags are contiguous 16B.
// ws layout: wqT(65536) wkT wvT wpT | w1T (1024x256) | w2T (256x1024) = 1.5MB
// ---------------------------------------------------------------------------
__global__ void kt_transpose(const u16* __restrict__ wq, const u16* __restrict__ wk,
                             const u16* __restrict__ wv, const u16* __restrict__ wp,
                             const u16* __restrict__ w1, const u16* __restrict__ w2,
                             u16* __restrict__ out)
{
    const bool f32m = detect_f32(wq);
    int idx = blockIdx.x * 256 + threadIdx.x;     // exactly 786432 threads
    const u16* s; int j;
    if (idx < 262144) {
        int m = idx >> 16, rem = idx & 65535, n = rem >> 8, r = rem & 255;
        s = (m == 0) ? wq : (m == 1) ? wk : (m == 2) ? wv : wp;
        j = r * 256 + n;
    } else if (idx < 524288) {
        int rem = idx - 262144, n = rem >> 8, r = rem & 255;   // n<1024, r<256
        s = w1; j = r * 1024 + n;
    } else {
        int rem = idx - 524288, n = rem >> 10, k = rem & 1023; // n<256, k<1024
        s = w2; j = k * 256 + n;
    }
    out[idx] = f32m ? f2b(reinterpret_cast<const float*>(s)[j]) : s[j];
}

// ---------------------------------------------------------------------------
// Attention megakernel: 1 block per window (2048 blocks, 256 threads = 4 waves)
// gather+roll+LN1 -> QKV -> per-head softmax(QK^T*s + bias + mask) V -> proj
// -> x2 = x + out (scatter with inverse roll), written INTO d_out (mode dtype).
// ---------------------------------------------------------------------------
#define LDA 264   // 256 + 8 pad
#define LDV 72    // 64 + 8 pad
#define LDP 40    // 32 + 8 pad

__global__ __launch_bounds__(256, 1)
void kt_attn(const u16* __restrict__ x,
             const u16* __restrict__ ln1g, const u16* __restrict__ ln1b,
             const u16* __restrict__ wqT, const u16* __restrict__ bq,
             const u16* __restrict__ wkT, const u16* __restrict__ bk,
             const u16* __restrict__ wvT, const u16* __restrict__ bv,
             const u16* __restrict__ wpT, const u16* __restrict__ bp,
             const u16* __restrict__ relb, const int* __restrict__ posi,
             const u16* __restrict__ amask, u16* __restrict__ x2)
{
    __shared__ __align__(16) u16 Xl[64 * LDA];    // X_ln, later reused as O
    __shared__ __align__(16) u16 Qb[64 * LDA];
    __shared__ __align__(16) u16 Kb[64 * LDA];
    __shared__ __align__(16) u16 Vt[256 * LDV];   // V transposed: [col][token]
    __shared__ __align__(16) u16 Ps4[4 * 64 * LDP]; // per-wave P scratch

    const bool f32m = detect_f32(x);
    const int tid = threadIdx.x;
    const int w = tid >> 6, lane = tid & 63, quad = lane >> 4, l16 = lane & 15;
    const int wi = blockIdx.x, b = wi >> 6, widx = wi & 63, wh = widx >> 3, ww = widx & 7;
    u16* Ps = Ps4 + w * 64 * LDP;

    // ---- phase 1: gather (roll -4,-4) + LN1 -> Xl ----
    {
        int r = tid >> 2, p = tid & 3;           // 4 threads per token row
        int ir = ((wh << 3) + (r >> 3) + 4) & 63;
        int ic = ((ww << 3) + (r & 7) + 4) & 63;
        int off0 = (b * 4096 + ir * 64 + ic) * 256 + p * 64;
        float v[64];
        float s = 0.f;
        if (f32m) {
            const float* src = reinterpret_cast<const float*>(x) + off0;
            #pragma unroll
            for (int t = 0; t < 16; ++t) {
                float4 d = *reinterpret_cast<const float4*>(src + t * 4);
                v[t*4+0]=d.x; v[t*4+1]=d.y; v[t*4+2]=d.z; v[t*4+3]=d.w;
                s += d.x + d.y + d.z + d.w;
            }
        } else {
            const u16* src = x + off0;
            #pragma unroll
            for (int t = 0; t < 8; ++t) {
                short8 d = ld8(src + t * 8);
                #pragma unroll
                for (int e = 0; e < 8; ++e) { float f = b2f((u16)d[e]); v[t*8+e] = f; s += f; }
            }
        }
        float s2 = 0.f;
        #pragma unroll
        for (int t = 0; t < 64; ++t) s2 += v[t] * v[t];
        s  += __shfl_xor(s, 1);  s  += __shfl_xor(s, 2);
        s2 += __shfl_xor(s2, 1); s2 += __shfl_xor(s2, 2);
        float mu = s * (1.f / 256.f);
        float rstd = rsqrtf(s2 * (1.f / 256.f) - mu * mu + 1e-5f);
        u16* dst = Xl + r * LDA + p * 64;
        #pragma unroll
        for (int t = 0; t < 64; ++t)
            dst[t] = f2b((v[t] - mu) * rstd * ldx(ln1g, p*64 + t, f32m) + ldx(ln1b, p*64 + t, f32m));
    }
    __syncthreads();

    // ---- phase 2: Q,K,V = Xl @ W + b  (wave w -> output cols [64w,64w+64)) ----
    #pragma unroll
    for (int m = 0; m < 3; ++m) {
        const u16* wt = (m == 0) ? wqT : (m == 1) ? wkT : wvT;
        const u16* bs = (m == 0) ? bq  : (m == 1) ? bk  : bv;
        f32x4 acc[4][4];
        #pragma unroll
        for (int mt = 0; mt < 4; ++mt)
            #pragma unroll
            for (int nt = 0; nt < 4; ++nt) acc[mt][nt] = fzero();
        #pragma unroll
        for (int ks = 0; ks < 8; ++ks) {
            short8 a[4], bb[4];
            #pragma unroll
            for (int mt = 0; mt < 4; ++mt)
                a[mt] = ld8(Xl + (mt * 16 + l16) * LDA + ks * 32 + quad * 8);
            #pragma unroll
            for (int nt = 0; nt < 4; ++nt)
                bb[nt] = ld8(wt + (w * 64 + nt * 16 + l16) * 256 + ks * 32 + quad * 8);
            #pragma unroll
            for (int mt = 0; mt < 4; ++mt)
                #pragma unroll
                for (int nt = 0; nt < 4; ++nt) acc[mt][nt] = mfma16(a[mt], bb[nt], acc[mt][nt]);
        }
        #pragma unroll
        for (int nt = 0; nt < 4; ++nt) {
            int col = w * 64 + nt * 16 + l16;
            float bv_ = ldx(bs, col, f32m);
            #pragma unroll
            for (int mt = 0; mt < 4; ++mt)
                #pragma unroll
                for (int r = 0; r < 4; ++r) {
                    int row = mt * 16 + quad * 4 + r;     // C layout: col=l16, row=quad*4+reg
                    u16 val = f2b(acc[mt][nt][r] + bv_);
                    if (m == 0)      Qb[row * LDA + col] = val;
                    else if (m == 1) Kb[row * LDA + col] = val;
                    else             Vt[col * LDV + row] = val;   // transposed for PV B-frags
                }
        }
    }
    __syncthreads();

    // ---- phase 3: per-head attention (wave w -> heads w and w+4) ----
    #pragma unroll
    for (int t = 0; t < 2; ++t) {
        const int h = t * 4 + w, hoff = h * 32;
        f32x4 sa[4][4];
        {
            short8 qa[4];
            #pragma unroll
            for (int mt = 0; mt < 4; ++mt)
                qa[mt] = ld8(Qb + (mt * 16 + l16) * LDA + hoff + quad * 8);
            #pragma unroll
            for (int nt = 0; nt < 4; ++nt) {
                short8 kb = ld8(Kb + (nt * 16 + l16) * LDA + hoff + quad * 8);
                #pragma unroll
                for (int mt = 0; mt < 4; ++mt) sa[mt][nt] = mfma16(qa[mt], kb, fzero());
            }
        }
        // scale + relative-position bias + shift mask
        #pragma unroll
        for (int mt = 0; mt < 4; ++mt)
            #pragma unroll
            for (int nt = 0; nt < 4; ++nt) {
                int c = nt * 16 + l16;
                #pragma unroll
                for (int r = 0; r < 4; ++r) {
                    int row = mt * 16 + quad * 4 + r;
                    int pi = posi[row * 64 + c];
                    sa[mt][nt][r] = sa[mt][nt][r] * 0.17677669529663687f
                                  + ldx(relb, pi * 8 + h, f32m)
                                  + ldx(amask, widx * 4096 + row * 64 + c, f32m);
                }
            }
        // softmax: row lives in 16 lanes of one quad (reduce over lane bits 0..3)
        float mx[4][4], sm[4][4];
        #pragma unroll
        for (int mt = 0; mt < 4; ++mt)
            #pragma unroll
            for (int r = 0; r < 4; ++r) {
                float m0 = fmaxf(fmaxf(sa[mt][0][r], sa[mt][1][r]),
                                 fmaxf(sa[mt][2][r], sa[mt][3][r]));
                m0 = fmaxf(m0, __shfl_xor(m0, 1)); m0 = fmaxf(m0, __shfl_xor(m0, 2));
                m0 = fmaxf(m0, __shfl_xor(m0, 4)); m0 = fmaxf(m0, __shfl_xor(m0, 8));
                mx[mt][r] = m0; sm[mt][r] = 0.f;
            }
        #pragma unroll
        for (int mt = 0; mt < 4; ++mt)
            #pragma unroll
            for (int nt = 0; nt < 4; ++nt)
                #pragma unroll
                for (int r = 0; r < 4; ++r) {
                    float e = __expf(sa[mt][nt][r] - mx[mt][r]);
                    sa[mt][nt][r] = e; sm[mt][r] += e;
                }
        #pragma unroll
        for (int mt = 0; mt < 4; ++mt)
            #pragma unroll
            for (int r = 0; r < 4; ++r) {
                float s0 = sm[mt][r];
                s0 += __shfl_xor(s0, 1); s0 += __shfl_xor(s0, 2);
                s0 += __shfl_xor(s0, 4); s0 += __shfl_xor(s0, 8);
                sm[mt][r] = 1.f / s0;
            }
        // P (C-layout) -> LDS -> A-layout, PV in two 32-wide k chunks
        f32x4 oa[4][2];
        #pragma unroll
        for (int mt = 0; mt < 4; ++mt) { oa[mt][0] = fzero(); oa[mt][1] = fzero(); }
        #pragma unroll
        for (int half = 0; half < 2; ++half) {
            #pragma unroll
            for (int mt = 0; mt < 4; ++mt)
                #pragma unroll
                for (int ntl = 0; ntl < 2; ++ntl) {
                    int nt = half * 2 + ntl;
                    #pragma unroll
                    for (int r = 0; r < 4; ++r) {
                        int row = mt * 16 + quad * 4 + r;
                        Ps[row * LDP + ntl * 16 + l16] = f2b(sa[mt][nt][r] * sm[mt][r]);
                    }
                }
            asm volatile("s_waitcnt lgkmcnt(0)" ::: "memory");  // wave-local RAW on Ps
            #pragma unroll
            for (int mt = 0; mt < 4; ++mt) {
                short8 pa = ld8(Ps + (mt * 16 + l16) * LDP + quad * 8);
                #pragma unroll
                for (int ct = 0; ct < 2; ++ct) {
                    short8 vb = ld8(Vt + (hoff + ct * 16 + l16) * LDV + half * 32 + quad * 8);
                    oa[mt][ct] = mfma16(pa, vb, oa[mt][ct]);
                }
            }
            asm volatile("s_waitcnt lgkmcnt(0)" ::: "memory");
        }
        // write O into Xl (dead after phase 2); disjoint cols per head
        #pragma unroll
        for (int mt = 0; mt < 4; ++mt)
            #pragma unroll
            for (int ct = 0; ct < 2; ++ct) {
                int col = hoff + ct * 16 + l16;
                #pragma unroll
                for (int r = 0; r < 4; ++r)
                    Xl[(mt * 16 + quad * 4 + r) * LDA + col] = f2b(oa[mt][ct][r]);
            }
    }
    __syncthreads();

    // ---- phase 4: proj + residual + scatter (reverse window + roll +4) ----
    {
        f32x4 acc[4][4];
        #pragma unroll
        for (int mt = 0; mt < 4; ++mt)
            #pragma unroll
            for (int nt = 0; nt < 4; ++nt) acc[mt][nt] = fzero();
        #pragma unroll
        for (int ks = 0; ks < 8; ++ks) {
            short8 a[4], bb[4];
            #pragma unroll
            for (int mt = 0; mt < 4; ++mt)
                a[mt] = ld8(Xl + (mt * 16 + l16) * LDA + ks * 32 + quad * 8);
            #pragma unroll
            for (int nt = 0; nt < 4; ++nt)
                bb[nt] = ld8(wpT + (w * 64 + nt * 16 + l16) * 256 + ks * 32 + quad * 8);
            #pragma unroll
            for (int mt = 0; mt < 4; ++mt)
                #pragma unroll
                for (int nt = 0; nt < 4; ++nt) acc[mt][nt] = mfma16(a[mt], bb[nt], acc[mt][nt]);
        }
        #pragma unroll
        for (int nt = 0; nt < 4; ++nt) {
            int col = w * 64 + nt * 16 + l16;
            float bpv = ldx(bp, col, f32m);
            #pragma unroll
            for (int mt = 0; mt < 4; ++mt)
                #pragma unroll
                for (int r = 0; r < 4; ++r) {
                    int row = mt * 16 + quad * 4 + r;
                    int ir = ((wh << 3) + (row >> 3) + 4) & 63;  // inverse roll == gather map
                    int ic = ((ww << 3) + (row & 7) + 4) & 63;
                    int off = (b * 4096 + ir * 64 + ic) * 256 + col;
                    float val = ldx(x, off, f32m) + acc[mt][nt][r] + bpv;
                    if (f32m) reinterpret_cast<float*>(x2)[off] = val;
                    else      x2[off] = f2b(val);
                }
        }
    }
}

// ---------------------------------------------------------------------------
// Fused MLP: LN2 -> (a2 @ w1 + b1) -> GELU -> (@ w2 + b2) -> + x2, per 128 rows.
// x2 lives in d_out (mode dtype); block reads its rows then overwrites in place.
// ---------------------------------------------------------------------------
#define LDM 264
#define LDH 136

__global__ __launch_bounds__(256, 1)
void kt_mlp(u16* __restrict__ x2, const u16* __restrict__ xprobe,
            const u16* __restrict__ ln2g, const u16* __restrict__ ln2b,
            const u16* __restrict__ w1T, const u16* __restrict__ b1,
            const u16* __restrict__ w2T, const u16* __restrict__ b2)
{
    __shared__ __align__(16) u16 Ab[128 * LDM];   // LN2 output tile (128 x 256)
    __shared__ __align__(16) u16 Hb[128 * LDH];   // GELU(h) chunk   (128 x 128)

    const bool f32m = detect_f32(xprobe);
    const int tid = threadIdx.x;
    const int w = tid >> 6, lane = tid & 63, quad = lane >> 4, l16 = lane & 15;
    const int m0 = blockIdx.x * 128;

    // ---- LN2 -> Ab (bf16) ----
    {
        int r = tid >> 1, hf = tid & 1;           // 2 threads per row
        int off0 = (m0 + r) * 256 + hf * 128;
        float v[128];
        float s = 0.f, s2 = 0.f;
        if (f32m) {
            const float* src = reinterpret_cast<const float*>(x2) + off0;
            #pragma unroll
            for (int t = 0; t < 32; ++t) {
                float4 d = *reinterpret_cast<const float4*>(src + t * 4);
                v[t*4+0]=d.x; v[t*4+1]=d.y; v[t*4+2]=d.z; v[t*4+3]=d.w;
                s += d.x + d.y + d.z + d.w;
                s2 += d.x*d.x + d.y*d.y + d.z*d.z + d.w*d.w;
            }
        } else {
            const u16* src = x2 + off0;
            #pragma unroll
            for (int t = 0; t < 16; ++t) {
                short8 d = ld8(src + t * 8);
                #pragma unroll
                for (int e = 0; e < 8; ++e) {
                    float f = b2f((u16)d[e]); v[t*8+e] = f; s += f; s2 += f * f;
                }
            }
        }
        s += __shfl_xor(s, 1); s2 += __shfl_xor(s2, 1);
        float mu = s * (1.f / 256.f);
        float rstd = rsqrtf(s2 * (1.f / 256.f) - mu * mu + 1e-5f);
        u16* dst = Ab + r * LDM + hf * 128;
        #pragma unroll
        for (int t = 0; t < 128; ++t) {
            int c = hf * 128 + t;
            dst[t] = f2b((v[t] - mu) * rstd * ldx(ln2g, c, f32m) + ldx(ln2b, c, f32m));
        }
    }
    __syncthreads();

    const int rh = (w >> 1) * 64;                 // wave row half
    const int ch = (w & 1) * 64;                  // gemm1 col quarter (of 128 chunk)
    const int c2 = (w & 1) * 128;                 // gemm2 col half (of 256)
    f32x4 acc2[4][8];
    #pragma unroll
    for (int mt = 0; mt < 4; ++mt)
        #pragma unroll
        for (int nt = 0; nt < 8; ++nt) acc2[mt][nt] = fzero();

    for (int hc = 0; hc < 8; ++hc) {
        // GEMM1 chunk: (128 x 256) @ (256 x 128) -> wave tile 64x64
        f32x4 acc1[4][4];
        #pragma unroll
        for (int mt = 0; mt < 4; ++mt)
            #pragma unroll
            for (int nt = 0; nt < 4; ++nt) acc1[mt][nt] = fzero();
        #pragma unroll
        for (int ks = 0; ks < 8; ++ks) {
            short8 a[4], bb[4];
            #pragma unroll
            for (int mt = 0; mt < 4; ++mt)
                a[mt] = ld8(Ab + (rh + mt * 16 + l16) * LDM + ks * 32 + quad * 8);
            #pragma unroll
            for (int nt = 0; nt < 4; ++nt)
                bb[nt] = ld8(w1T + (hc * 128 + ch + nt * 16 + l16) * 256 + ks * 32 + quad * 8);
            #pragma unroll
            for (int mt = 0; mt < 4; ++mt)
                #pragma unroll
                for (int nt = 0; nt < 4; ++nt) acc1[mt][nt] = mfma16(a[mt], bb[nt], acc1[mt][nt]);
        }
        // + b1, exact GELU, -> Hb
        #pragma unroll
        for (int nt = 0; nt < 4; ++nt) {
            int c = ch + nt * 16 + l16;
            float b1v = ldx(b1, hc * 128 + c, f32m);
            #pragma unroll
            for (int mt = 0; mt < 4; ++mt)
                #pragma unroll
                for (int r = 0; r < 4; ++r) {
                    int row = rh + mt * 16 + quad * 4 + r;
                    float vv = acc1[mt][nt][r] + b1v;
                    Hb[row * LDH + c] = f2b(0.5f * vv * (1.f + erff(vv * 0.70710678118654752f)));
                }
        }
        __syncthreads();
        // GEMM2 chunk: (128 x 128) @ (128 x 256) accumulate -> wave tile 64x128
        #pragma unroll
        for (int ks = 0; ks < 4; ++ks) {
            short8 a[4];
            #pragma unroll
            for (int mt = 0; mt < 4; ++mt)
                a[mt] = ld8(Hb + (rh + mt * 16 + l16) * LDH + ks * 32 + quad * 8);
            #pragma unroll
            for (int nt = 0; nt < 8; ++nt) {
                short8 bb = ld8(w2T + (c2 + nt * 16 + l16) * 1024 + hc * 128 + ks * 32 + quad * 8);
                #pragma unroll
                for (int mt = 0; mt < 4; ++mt) acc2[mt][nt] = mfma16(a[mt], bb, acc2[mt][nt]);
            }
        }
        __syncthreads();
    }
    // epilogue: + b2 + x2 residual, in place over x2 (= d_out), mode dtype
    #pragma unroll
    for (int nt = 0; nt < 8; ++nt) {
        int c = c2 + nt * 16 + l16;
        float b2v = ldx(b2, c, f32m);
        #pragma unroll
        for (int mt = 0; mt < 4; ++mt)
            #pragma unroll
            for (int r = 0; r < 4; ++r) {
                int row = m0 + rh + mt * 16 + quad * 4 + r;
                int off = row * 256 + c;
                float val = acc2[mt][nt][r] + b2v + ldx(x2, off, f32m);
                if (f32m) reinterpret_cast<float*>(x2)[off] = val;
                else      x2[off] = f2b(val);
            }
    }
}

// ---------------------------------------------------------------------------
extern "C" void kernel_launch(void* const* d_in, const int* in_sizes, int n_in,
                              void* d_out, int out_size, void* d_ws, size_t ws_size,
                              hipStream_t stream)
{
    (void)in_sizes; (void)n_in; (void)out_size; (void)ws_size;
    const u16* x    = (const u16*)d_in[0];
    const u16* ln1g = (const u16*)d_in[1];
    const u16* ln1b = (const u16*)d_in[2];
    const u16* wq   = (const u16*)d_in[3];
    const u16* bq   = (const u16*)d_in[4];
    const u16* wk   = (const u16*)d_in[5];
    const u16* bk   = (const u16*)d_in[6];
    const u16* wv   = (const u16*)d_in[7];
    const u16* bv   = (const u16*)d_in[8];
    const u16* wp   = (const u16*)d_in[9];
    const u16* bp   = (const u16*)d_in[10];
    const u16* relb = (const u16*)d_in[11];
    const u16* ln2g = (const u16*)d_in[12];
    const u16* ln2b = (const u16*)d_in[13];
    const u16* w1   = (const u16*)d_in[14];
    const u16* b1   = (const u16*)d_in[15];
    const u16* w2   = (const u16*)d_in[16];
    const u16* b2   = (const u16*)d_in[17];
    const int* posi = (const int*)d_in[18];
    const u16* amask= (const u16*)d_in[19];

    u16* wT = (u16*)d_ws;                         // 786432 u16 = 1.5 MB only
    u16* x2 = (u16*)d_out;                        // residual stream lives in d_out

    kt_transpose<<<3072, 256, 0, stream>>>(wq, wk, wv, wp, w1, w2, wT);

    kt_attn<<<2048, 256, 0, stream>>>(x, ln1g, ln1b,
                                      wT, bq, wT + 65536, bk, wT + 131072, bv,
                                      wT + 196608, bp, relb, posi, amask, x2);

    kt_mlp<<<1024, 256, 0, stream>>>(x2, x, ln2g, ln2b,
                                     wT + 262144, b1, wT + 524288, b2);
}

// Round 4
// 977.825 us; speedup vs baseline: 1.5731x; 1.5731x over previous
//
#include <hip/hip_runtime.h>
#include <math.h>

typedef unsigned short u16;
typedef unsigned int   u32;
typedef __attribute__((ext_vector_type(8))) short short8;
typedef __attribute__((ext_vector_type(4))) float f32x4;

#define DEV static __device__ __forceinline__
#define LGKM0 asm volatile("s_waitcnt lgkmcnt(0)" ::: "memory")

DEV float b2f(u16 u) { union { u32 i; float f; } c; c.i = ((u32)u) << 16; return c.f; }
DEV u16 f2b(float f) {
    union { float f; u32 i; } c; c.f = f;
    return (u16)((c.i + 0x7fffu + ((c.i >> 16) & 1u)) >> 16);
}
DEV f32x4 fzero() { f32x4 z = {0.f, 0.f, 0.f, 0.f}; return z; }
DEV f32x4 mfma16(short8 a, short8 b, f32x4 c) {
    return __builtin_amdgcn_mfma_f32_16x16x32_bf16(a, b, c, 0, 0, 0);
}
DEV short8 ld8(const u16* p) { return *reinterpret_cast<const short8*>(p); }

// Runtime dtype probe (verified R3: dataset is f32; keep dual-mode for safety).
DEV bool detect_f32(const u16* t) {
    int g = 0;
    #pragma unroll
    for (int i = 0; i < 64; ++i) {
        float v = b2f(t[2 * i]);
        if (!(fabsf(v) < 64.0f)) ++g;
    }
    return g >= 8;
}
DEV float ldx(const u16* p, int i, bool f32m) {
    return f32m ? reinterpret_cast<const float*>(p)[i] : b2f(p[i]);
}

// Branchless exact-GELU via Abramowitz-Stegun 7.1.26 erf (|err| <= 1.5e-7).
DEV float gelu(float x) {
    float ax = fabsf(x) * 0.70710678118654752f;   // |x|/sqrt(2)
    float t = 1.f / (1.f + 0.3275911f * ax);
    float y = t * (0.254829592f + t * (-0.284496736f + t * (1.421413741f +
              t * (-1.453152027f + t * 1.061405429f))));
    float er = 1.f - y * __expf(-ax * ax);        // erf(|x|/sqrt2)
    er = copysignf(er, x);
    return 0.5f * x * (1.f + er);
}

// ---------------------------------------------------------------------------
// Weight pre-transpose -> bf16 wT[n][k].
// ws: wqT(65536) wkT wvT wpT | w1T(1024x256) | w2T(256x1024) | biasF | amaskF
// ---------------------------------------------------------------------------
__global__ void kt_transpose(const u16* __restrict__ wq, const u16* __restrict__ wk,
                             const u16* __restrict__ wv, const u16* __restrict__ wp,
                             const u16* __restrict__ w1, const u16* __restrict__ w2,
                             u16* __restrict__ out)
{
    const bool f32m = detect_f32(wq);
    int idx = blockIdx.x * 256 + threadIdx.x;     // exactly 786432 threads
    const u16* s; int j;
    if (idx < 262144) {
        int m = idx >> 16, rem = idx & 65535, n = rem >> 8, r = rem & 255;
        s = (m == 0) ? wq : (m == 1) ? wk : (m == 2) ? wv : wp;
        j = r * 256 + n;
    } else if (idx < 524288) {
        int rem = idx - 262144, n = rem >> 8, r = rem & 255;
        s = w1; j = r * 1024 + n;
    } else {
        int rem = idx - 524288, n = rem >> 10, k = rem & 1023;
        s = w2; j = k * 256 + n;
    }
    out[idx] = f32m ? f2b(reinterpret_cast<const float*>(s)[j]) : s[j];
}

// Pre-expand rel-pos bias (posi gather) and attention mask to flat f32 tables.
__global__ void kt_prep(const u16* __restrict__ relb, const u16* __restrict__ amask,
                        const int* __restrict__ posi, float* __restrict__ biasF,
                        float* __restrict__ amaskF, const u16* __restrict__ probe)
{
    const bool f32m = detect_f32(probe);
    int idx = blockIdx.x * 256 + threadIdx.x;     // 294912 threads
    if (idx < 32768) {                            // biasF[h][row*64+col]
        int h = idx >> 12, rc = idx & 4095;
        biasF[idx] = ldx(relb, posi[rc] * 8 + h, f32m);
    } else {
        int i = idx - 32768;                      // amaskF[widx*4096 + rc]
        amaskF[i] = ldx(amask, i, f32m);
    }
}

// ---------------------------------------------------------------------------
// Attention: 2048 blocks x 256 thr (4 waves). Wave w owns heads 2w, 2w+1.
// Per-wave LDS strip does all layout transposes (Q/K/V/P) -> no big QKV bufs.
// LDS 55 KB -> 2 blocks/CU.
// ---------------------------------------------------------------------------
#define LDA 264    // Xl row stride
#define SSTR 44    // strip stride (token-major): 4-row quads hit distinct banks
#define VSTR 76    // strip stride for transposed V (dim-major)

__global__ __launch_bounds__(256, 2)
void kt_attn(const u16* __restrict__ x,
             const u16* __restrict__ ln1g, const u16* __restrict__ ln1b,
             const u16* __restrict__ wqT, const u16* __restrict__ bq,
             const u16* __restrict__ wkT, const u16* __restrict__ bk,
             const u16* __restrict__ wvT, const u16* __restrict__ bv,
             const u16* __restrict__ wpT, const u16* __restrict__ bp,
             const float* __restrict__ biasF, const float* __restrict__ amaskF,
             u16* __restrict__ x2)
{
    __shared__ __align__(16) u16 Xl[64 * LDA];        // LN1 out, later O
    __shared__ __align__(16) u16 Strip[4 * 64 * SSTR];

    const bool f32m = detect_f32(x);
    const int tid = threadIdx.x;
    const int w = tid >> 6, lane = tid & 63, quad = lane >> 4, l16 = lane & 15;
    const int wi = blockIdx.x, b = wi >> 6, widx = wi & 63, wh = widx >> 3, ww = widx & 7;
    u16* St = Strip + w * 64 * SSTR;

    // ---- phase 1: gather (roll -4,-4) + LN1 -> Xl ----
    {
        int r = tid >> 2, p = tid & 3;
        int ir = ((wh << 3) + (r >> 3) + 4) & 63;
        int ic = ((ww << 3) + (r & 7) + 4) & 63;
        int off0 = (b * 4096 + ir * 64 + ic) * 256 + p * 64;
        float v[64];
        float s = 0.f;
        if (f32m) {
            const float* src = reinterpret_cast<const float*>(x) + off0;
            #pragma unroll
            for (int t = 0; t < 16; ++t) {
                float4 d = *reinterpret_cast<const float4*>(src + t * 4);
                v[t*4+0]=d.x; v[t*4+1]=d.y; v[t*4+2]=d.z; v[t*4+3]=d.w;
                s += d.x + d.y + d.z + d.w;
            }
        } else {
            const u16* src = x + off0;
            #pragma unroll
            for (int t = 0; t < 8; ++t) {
                short8 d = ld8(src + t * 8);
                #pragma unroll
                for (int e = 0; e < 8; ++e) { float f = b2f((u16)d[e]); v[t*8+e] = f; s += f; }
            }
        }
        float s2 = 0.f;
        #pragma unroll
        for (int t = 0; t < 64; ++t) s2 += v[t] * v[t];
        s  += __shfl_xor(s, 1);  s  += __shfl_xor(s, 2);
        s2 += __shfl_xor(s2, 1); s2 += __shfl_xor(s2, 2);
        float mu = s * (1.f / 256.f);
        float rstd = rsqrtf(s2 * (1.f / 256.f) - mu * mu + 1e-5f);
        u16* dst = Xl + r * LDA + p * 64;
        #pragma unroll
        for (int t = 0; t < 64; ++t)
            dst[t] = f2b((v[t]-mu)*rstd*ldx(ln1g, p*64+t, f32m) + ldx(ln1b, p*64+t, f32m));
    }
    __syncthreads();

    // ---- phase 2: per-head Q/K/V GEMMs -> register fragments via strip ----
    short8 qa[2][4], kb[2][4], vb[2][4];
    #pragma unroll
    for (int t = 0; t < 2; ++t) {
        const int hoff = w * 64 + t * 32;         // head h = 2w+t
        // --- Q (scale folded in) ---
        {
            f32x4 acc[4][2];
            #pragma unroll
            for (int mt = 0; mt < 4; ++mt) { acc[mt][0] = fzero(); acc[mt][1] = fzero(); }
            #pragma unroll
            for (int ks = 0; ks < 8; ++ks) {
                short8 a[4], bb[2];
                #pragma unroll
                for (int mt = 0; mt < 4; ++mt)
                    a[mt] = ld8(Xl + (mt*16+l16)*LDA + ks*32 + quad*8);
                #pragma unroll
                for (int nt = 0; nt < 2; ++nt)
                    bb[nt] = ld8(wqT + (hoff+nt*16+l16)*256 + ks*32 + quad*8);
                #pragma unroll
                for (int mt = 0; mt < 4; ++mt)
                    #pragma unroll
                    for (int nt = 0; nt < 2; ++nt) acc[mt][nt] = mfma16(a[mt], bb[nt], acc[mt][nt]);
            }
            #pragma unroll
            for (int nt = 0; nt < 2; ++nt) {
                float bz = ldx(bq, hoff + nt*16 + l16, f32m);
                #pragma unroll
                for (int mt = 0; mt < 4; ++mt)
                    #pragma unroll
                    for (int r = 0; r < 4; ++r)
                        St[(mt*16+quad*4+r)*SSTR + nt*16+l16] =
                            f2b((acc[mt][nt][r] + bz) * 0.17677669529663687f);
            }
            LGKM0;
            #pragma unroll
            for (int mt = 0; mt < 4; ++mt)
                qa[t][mt] = ld8(St + (mt*16+l16)*SSTR + quad*8);
            LGKM0;
        }
        // --- K ---
        {
            f32x4 acc[4][2];
            #pragma unroll
            for (int mt = 0; mt < 4; ++mt) { acc[mt][0] = fzero(); acc[mt][1] = fzero(); }
            #pragma unroll
            for (int ks = 0; ks < 8; ++ks) {
                short8 a[4], bb[2];
                #pragma unroll
                for (int mt = 0; mt < 4; ++mt)
                    a[mt] = ld8(Xl + (mt*16+l16)*LDA + ks*32 + quad*8);
                #pragma unroll
                for (int nt = 0; nt < 2; ++nt)
                    bb[nt] = ld8(wkT + (hoff+nt*16+l16)*256 + ks*32 + quad*8);
                #pragma unroll
                for (int mt = 0; mt < 4; ++mt)
                    #pragma unroll
                    for (int nt = 0; nt < 2; ++nt) acc[mt][nt] = mfma16(a[mt], bb[nt], acc[mt][nt]);
            }
            #pragma unroll
            for (int nt = 0; nt < 2; ++nt) {
                float bz = ldx(bk, hoff + nt*16 + l16, f32m);
                #pragma unroll
                for (int mt = 0; mt < 4; ++mt)
                    #pragma unroll
                    for (int r = 0; r < 4; ++r)
                        St[(mt*16+quad*4+r)*SSTR + nt*16+l16] = f2b(acc[mt][nt][r] + bz);
            }
            LGKM0;
            #pragma unroll
            for (int j = 0; j < 4; ++j)           // B-frag: n=token, k=dim
                kb[t][j] = ld8(St + (j*16+l16)*SSTR + quad*8);
            LGKM0;
        }
        // --- V (strip transposed: [dim][token]) ---
        {
            f32x4 acc[4][2];
            #pragma unroll
            for (int mt = 0; mt < 4; ++mt) { acc[mt][0] = fzero(); acc[mt][1] = fzero(); }
            #pragma unroll
            for (int ks = 0; ks < 8; ++ks) {
                short8 a[4], bb[2];
                #pragma unroll
                for (int mt = 0; mt < 4; ++mt)
                    a[mt] = ld8(Xl + (mt*16+l16)*LDA + ks*32 + quad*8);
                #pragma unroll
                for (int nt = 0; nt < 2; ++nt)
                    bb[nt] = ld8(wvT + (hoff+nt*16+l16)*256 + ks*32 + quad*8);
                #pragma unroll
                for (int mt = 0; mt < 4; ++mt)
                    #pragma unroll
                    for (int nt = 0; nt < 2; ++nt) acc[mt][nt] = mfma16(a[mt], bb[nt], acc[mt][nt]);
            }
            #pragma unroll
            for (int nt = 0; nt < 2; ++nt) {
                float bz = ldx(bv, hoff + nt*16 + l16, f32m);
                #pragma unroll
                for (int mt = 0; mt < 4; ++mt)
                    #pragma unroll
                    for (int r = 0; r < 4; ++r)
                        St[(nt*16+l16)*VSTR + mt*16+quad*4+r] = f2b(acc[mt][nt][r] + bz);
            }
            LGKM0;
            #pragma unroll
            for (int half = 0; half < 2; ++half)
                #pragma unroll
                for (int ct = 0; ct < 2; ++ct)    // B-frag: n=dim, k=token
                    vb[t][half*2+ct] = ld8(St + (ct*16+l16)*VSTR + half*32 + quad*8);
            LGKM0;
        }
    }
    __syncthreads();                              // all Xl reads done; O may overwrite

    // ---- phase 3: attention per head ----
    #pragma unroll
    for (int t = 0; t < 2; ++t) {
        const int hoff = w * 64 + t * 32;
        const int hb = (w*2 + t) * 4096, mb = widx * 4096;
        f32x4 sa[4][4];
        #pragma unroll
        for (int mt = 0; mt < 4; ++mt)
            #pragma unroll
            for (int nt = 0; nt < 4; ++nt) sa[mt][nt] = mfma16(qa[t][mt], kb[t][nt], fzero());
        #pragma unroll
        for (int mt = 0; mt < 4; ++mt)
            #pragma unroll
            for (int nt = 0; nt < 4; ++nt) {
                int c = nt*16 + l16;
                #pragma unroll
                for (int r = 0; r < 4; ++r) {
                    int rc = (mt*16+quad*4+r)*64 + c;
                    sa[mt][nt][r] += biasF[hb + rc] + amaskF[mb + rc];
                }
            }
        float mx[4][4], sm[4][4];
        #pragma unroll
        for (int mt = 0; mt < 4; ++mt)
            #pragma unroll
            for (int r = 0; r < 4; ++r) {
                float m0 = fmaxf(fmaxf(sa[mt][0][r], sa[mt][1][r]),
                                 fmaxf(sa[mt][2][r], sa[mt][3][r]));
                m0 = fmaxf(m0, __shfl_xor(m0, 1)); m0 = fmaxf(m0, __shfl_xor(m0, 2));
                m0 = fmaxf(m0, __shfl_xor(m0, 4)); m0 = fmaxf(m0, __shfl_xor(m0, 8));
                mx[mt][r] = m0; sm[mt][r] = 0.f;
            }
        #pragma unroll
        for (int mt = 0; mt < 4; ++mt)
            #pragma unroll
            for (int nt = 0; nt < 4; ++nt)
                #pragma unroll
                for (int r = 0; r < 4; ++r) {
                    float e = __expf(sa[mt][nt][r] - mx[mt][r]);
                    sa[mt][nt][r] = e; sm[mt][r] += e;
                }
        #pragma unroll
        for (int mt = 0; mt < 4; ++mt)
            #pragma unroll
            for (int r = 0; r < 4; ++r) {
                float s0 = sm[mt][r];
                s0 += __shfl_xor(s0, 1); s0 += __shfl_xor(s0, 2);
                s0 += __shfl_xor(s0, 4); s0 += __shfl_xor(s0, 8);
                sm[mt][r] = 1.f / s0;
            }
        f32x4 oa[4][2];
        #pragma unroll
        for (int mt = 0; mt < 4; ++mt) { oa[mt][0] = fzero(); oa[mt][1] = fzero(); }
        #pragma unroll
        for (int half = 0; half < 2; ++half) {
            #pragma unroll
            for (int mt = 0; mt < 4; ++mt)
                #pragma unroll
                for (int ntl = 0; ntl < 2; ++ntl) {
                    int nt = half*2 + ntl;
                    #pragma unroll
                    for (int r = 0; r < 4; ++r)
                        St[(mt*16+quad*4+r)*SSTR + ntl*16+l16] = f2b(sa[mt][nt][r]*sm[mt][r]);
                }
            LGKM0;
            #pragma unroll
            for (int mt = 0; mt < 4; ++mt) {
                short8 pa = ld8(St + (mt*16+l16)*SSTR + quad*8);
                #pragma unroll
                for (int ct = 0; ct < 2; ++ct)
                    oa[mt][ct] = mfma16(pa, vb[t][half*2+ct], oa[mt][ct]);
            }
            LGKM0;
        }
        #pragma unroll
        for (int mt = 0; mt < 4; ++mt)
            #pragma unroll
            for (int ct = 0; ct < 2; ++ct) {
                int col = hoff + ct*16 + l16;
                #pragma unroll
                for (int r = 0; r < 4; ++r)
                    Xl[(mt*16+quad*4+r)*LDA + col] = f2b(oa[mt][ct][r]);
            }
    }
    __syncthreads();

    // ---- phase 4: proj + residual + scatter ----
    {
        f32x4 acc[4][4];
        #pragma unroll
        for (int mt = 0; mt < 4; ++mt)
            #pragma unroll
            for (int nt = 0; nt < 4; ++nt) acc[mt][nt] = fzero();
        #pragma unroll
        for (int ks = 0; ks < 8; ++ks) {
            short8 a[4], bb[4];
            #pragma unroll
            for (int mt = 0; mt < 4; ++mt)
                a[mt] = ld8(Xl + (mt*16+l16)*LDA + ks*32 + quad*8);
            #pragma unroll
            for (int nt = 0; nt < 4; ++nt)
                bb[nt] = ld8(wpT + (w*64+nt*16+l16)*256 + ks*32 + quad*8);
            #pragma unroll
            for (int mt = 0; mt < 4; ++mt)
                #pragma unroll
                for (int nt = 0; nt < 4; ++nt) acc[mt][nt] = mfma16(a[mt], bb[nt], acc[mt][nt]);
        }
        #pragma unroll
        for (int nt = 0; nt < 4; ++nt) {
            int col = w*64 + nt*16 + l16;
            float bpv = ldx(bp, col, f32m);
            #pragma unroll
            for (int mt = 0; mt < 4; ++mt)
                #pragma unroll
                for (int r = 0; r < 4; ++r) {
                    int row = mt*16 + quad*4 + r;
                    int ir = ((wh << 3) + (row >> 3) + 4) & 63;
                    int ic = ((ww << 3) + (row & 7) + 4) & 63;
                    int off = (b*4096 + ir*64 + ic)*256 + col;
                    float val = ldx(x, off, f32m) + acc[mt][nt][r] + bpv;
                    if (f32m) reinterpret_cast<float*>(x2)[off] = val;
                    else      x2[off] = f2b(val);
                }
        }
    }
}

// ---------------------------------------------------------------------------
// Fused MLP: 2048 blocks x 64 rows. LDS 51 KB -> 3 blocks/CU.
// ---------------------------------------------------------------------------
#define LDM 264
#define LDH 140

__global__ __launch_bounds__(256, 3)
void kt_mlp(u16* __restrict__ x2, const u16* __restrict__ xprobe,
            const u16* __restrict__ ln2g, const u16* __restrict__ ln2b,
            const u16* __restrict__ w1T, const u16* __restrict__ b1,
            const u16* __restrict__ w2T, const u16* __restrict__ b2)
{
    __shared__ __align__(16) u16 Ab[64 * LDM];    // LN2 tile (64 x 256)
    __shared__ __align__(16) u16 Hb[64 * LDH];    // GELU chunk (64 x 128)

    const bool f32m = detect_f32(xprobe);
    const int tid = threadIdx.x;
    const int w = tid >> 6, lane = tid & 63, quad = lane >> 4, l16 = lane & 15;
    const int m0 = blockIdx.x * 64;

    // ---- LN2 -> Ab ----
    {
        int r = tid >> 2, p = tid & 3;
        int off0 = (m0 + r) * 256 + p * 64;
        float v[64];
        float s = 0.f;
        if (f32m) {
            const float* src = reinterpret_cast<const float*>(x2) + off0;
            #pragma unroll
            for (int t = 0; t < 16; ++t) {
                float4 d = *reinterpret_cast<const float4*>(src + t * 4);
                v[t*4+0]=d.x; v[t*4+1]=d.y; v[t*4+2]=d.z; v[t*4+3]=d.w;
                s += d.x + d.y + d.z + d.w;
            }
        } else {
            const u16* src = x2 + off0;
            #pragma unroll
            for (int t = 0; t < 8; ++t) {
                short8 d = ld8(src + t * 8);
                #pragma unroll
                for (int e = 0; e < 8; ++e) { float f = b2f((u16)d[e]); v[t*8+e] = f; s += f; }
            }
        }
        float s2 = 0.f;
        #pragma unroll
        for (int t = 0; t < 64; ++t) s2 += v[t] * v[t];
        s  += __shfl_xor(s, 1);  s  += __shfl_xor(s, 2);
        s2 += __shfl_xor(s2, 1); s2 += __shfl_xor(s2, 2);
        float mu = s * (1.f / 256.f);
        float rstd = rsqrtf(s2 * (1.f / 256.f) - mu * mu + 1e-5f);
        u16* dst = Ab + r * LDM + p * 64;
        #pragma unroll
        for (int t = 0; t < 64; ++t)
            dst[t] = f2b((v[t]-mu)*rstd*ldx(ln2g, p*64+t, f32m) + ldx(ln2b, p*64+t, f32m));
    }
    __syncthreads();

    f32x4 acc2[4][4];
    #pragma unroll
    for (int mt = 0; mt < 4; ++mt)
        #pragma unroll
        for (int nt = 0; nt < 4; ++nt) acc2[mt][nt] = fzero();

    for (int hc = 0; hc < 8; ++hc) {
        // GEMM1: (64x256)@(256x128 chunk); wave w -> 32 cols
        f32x4 acc1[4][2];
        #pragma unroll
        for (int mt = 0; mt < 4; ++mt) { acc1[mt][0] = fzero(); acc1[mt][1] = fzero(); }
        #pragma unroll
        for (int ks = 0; ks < 8; ++ks) {
            short8 a[4], bb[2];
            #pragma unroll
            for (int mt = 0; mt < 4; ++mt)
                a[mt] = ld8(Ab + (mt*16+l16)*LDM + ks*32 + quad*8);
            #pragma unroll
            for (int nt = 0; nt < 2; ++nt)
                bb[nt] = ld8(w1T + (hc*128 + w*32 + nt*16+l16)*256 + ks*32 + quad*8);
            #pragma unroll
            for (int mt = 0; mt < 4; ++mt)
                #pragma unroll
                for (int nt = 0; nt < 2; ++nt) acc1[mt][nt] = mfma16(a[mt], bb[nt], acc1[mt][nt]);
        }
        #pragma unroll
        for (int nt = 0; nt < 2; ++nt) {
            int c = w*32 + nt*16 + l16;
            float b1v = ldx(b1, hc*128 + c, f32m);
            #pragma unroll
            for (int mt = 0; mt < 4; ++mt)
                #pragma unroll
                for (int r = 0; r < 4; ++r)
                    Hb[(mt*16+quad*4+r)*LDH + c] = f2b(gelu(acc1[mt][nt][r] + b1v));
        }
        __syncthreads();
        // GEMM2: (64x128)@(128x256); wave w -> 64 cols, accumulate
        #pragma unroll
        for (int ks = 0; ks < 4; ++ks) {
            short8 a[4];
            #pragma unroll
            for (int mt = 0; mt < 4; ++mt)
                a[mt] = ld8(Hb + (mt*16+l16)*LDH + ks*32 + quad*8);
            #pragma unroll
            for (int nt = 0; nt < 4; ++nt) {
                short8 bb = ld8(w2T + (w*64+nt*16+l16)*1024 + hc*128 + ks*32 + quad*8);
                #pragma unroll
                for (int mt = 0; mt < 4; ++mt) acc2[mt][nt] = mfma16(a[mt], bb, acc2[mt][nt]);
            }
        }
        __syncthreads();
    }
    // epilogue: + b2 + residual, in place over x2 (= d_out)
    #pragma unroll
    for (int nt = 0; nt < 4; ++nt) {
        int col = w*64 + nt*16 + l16;
        float b2v = ldx(b2, col, f32m);
        #pragma unroll
        for (int mt = 0; mt < 4; ++mt)
            #pragma unroll
            for (int r = 0; r < 4; ++r) {
                int off = (m0 + mt*16 + quad*4 + r) * 256 + col;
                float val = acc2[mt][nt][r] + b2v + ldx(x2, off, f32m);
                if (f32m) reinterpret_cast<float*>(x2)[off] = val;
                else      x2[off] = f2b(val);
            }
    }
}

// ---------------------------------------------------------------------------
extern "C" void kernel_launch(void* const* d_in, const int* in_sizes, int n_in,
                              void* d_out, int out_size, void* d_ws, size_t ws_size,
                              hipStream_t stream)
{
    (void)in_sizes; (void)n_in; (void)out_size; (void)ws_size;
    const u16* x    = (const u16*)d_in[0];
    const u16* ln1g = (const u16*)d_in[1];
    const u16* ln1b = (const u16*)d_in[2];
    const u16* wq   = (const u16*)d_in[3];
    const u16* bq   = (const u16*)d_in[4];
    const u16* wk   = (const u16*)d_in[5];
    const u16* bk   = (const u16*)d_in[6];
    const u16* wv   = (const u16*)d_in[7];
    const u16* bv   = (const u16*)d_in[8];
    const u16* wp   = (const u16*)d_in[9];
    const u16* bp   = (const u16*)d_in[10];
    const u16* relb = (const u16*)d_in[11];
    const u16* ln2g = (const u16*)d_in[12];
    const u16* ln2b = (const u16*)d_in[13];
    const u16* w1   = (const u16*)d_in[14];
    const u16* b1   = (const u16*)d_in[15];
    const u16* w2   = (const u16*)d_in[16];
    const u16* b2   = (const u16*)d_in[17];
    const int* posi = (const int*)d_in[18];
    const u16* amask= (const u16*)d_in[19];

    u16*   wT     = (u16*)d_ws;                              // 1.5 MB
    float* biasF  = (float*)((char*)d_ws + 1572864);         // 128 KB
    float* amaskF = (float*)((char*)d_ws + 1703936);         // 1 MB
    u16*   x2     = (u16*)d_out;

    kt_transpose<<<3072, 256, 0, stream>>>(wq, wk, wv, wp, w1, w2, wT);
    kt_prep<<<1152, 256, 0, stream>>>(relb, amask, posi, biasF, amaskF, wq);

    kt_attn<<<2048, 256, 0, stream>>>(x, ln1g, ln1b,
                                      wT, bq, wT + 65536, bk, wT + 131072, bv,
                                      wT + 196608, bp, biasF, amaskF, x2);

    kt_mlp<<<2048, 256, 0, stream>>>(x2, x, ln2g, ln2b,
                                     wT + 262144, b1, wT + 524288, b2);
}